// Round 8
// baseline (759.779 us; speedup 1.0000x reference)
//
#include <hip/hip_runtime.h>
#include <hip/hip_bf16.h>
#include <cstdint>

#define N_TOK 4096
#define KTOP  64
#define DIM   1024
#define NLAT  16384
#define NBLK  512      // 2 blocks/CU -- co-residency guaranteed by resource math

typedef __bf16 bf16x8 __attribute__((ext_vector_type(8)));
typedef float  floatx4 __attribute__((ext_vector_type(4)));
typedef float  floatx2 __attribute__((ext_vector_type(2)));

#define GLOBAL_AS(p) ((const __attribute__((address_space(1))) void*)(p))
#define LDS_AS(p)    ((__attribute__((address_space(3))) void*)(p))

__device__ inline unsigned short f2bf(float f){
  unsigned int u = __float_as_uint(f);
  return (unsigned short)((u + 0x7fffu + ((u >> 16) & 1u)) >> 16);  // RNE
}

// Persistent-kernel grid barrier. Release flushes this XCD's L2; acquire invalidates.
__device__ inline void gridbar(unsigned* cnt, unsigned* gen){
  __threadfence();
  __syncthreads();
  if (threadIdx.x == 0){
    unsigned g = __hip_atomic_load(gen, __ATOMIC_RELAXED, __HIP_MEMORY_SCOPE_AGENT);
    unsigned a = __hip_atomic_fetch_add(cnt, 1u, __ATOMIC_ACQ_REL, __HIP_MEMORY_SCOPE_AGENT);
    if (a == NBLK - 1){
      __hip_atomic_store(cnt, 0u, __ATOMIC_RELAXED, __HIP_MEMORY_SCOPE_AGENT);
      __hip_atomic_store(gen, g + 1u, __ATOMIC_RELEASE, __HIP_MEMORY_SCOPE_AGENT);
    } else {
      while (__hip_atomic_load(gen, __ATOMIC_ACQUIRE, __HIP_MEMORY_SCOPE_AGENT) == g)
        __builtin_amdgcn_s_sleep(8);
    }
  }
  __syncthreads();
  __threadfence();
}

__global__ __launch_bounds__(256, 2) void fused(
    const float* __restrict__ x,  const float* __restrict__ y,
    const float* __restrict__ la, const int* __restrict__ li,
    const float* __restrict__ Wd, const float* __restrict__ bd,
    const float* __restrict__ pe, const float* __restrict__ pes,
    const float* __restrict__ Wsk, float* __restrict__ out,
    unsigned* __restrict__ bar,    // [0]=cnt [1]=gen (pre-zeroed by memset node)
    unsigned short* __restrict__ xb, unsigned short* __restrict__ wb,
    unsigned char* __restrict__ wdf,
    float* __restrict__ csp,   // [128][1024] colsum partials
    float* __restrict__ ssep,  // [512] sse partials
    float* __restrict__ sqp,   // [128] sumsq partials
    float* __restrict__ vp,    // [32] sum(colsum^2) partials
    float* __restrict__ sqf)   // [1] sumsq final
{
  __shared__ __align__(16) char smem[12352];
  const int bid = blockIdx.x;
  const int t   = threadIdx.x;

  // ================= P1: prep (3456 grid-strided units) =================
  for (int u = bid; u < 3456; u += NBLK){
    if (u < 1024){                       // x -> bf16
      int i0 = u * 1024 + t;
      #pragma unroll
      for (int i = 0; i < 4; i++){
        float4 v = ((const float4*)x)[i0 + i * 256];
        ushort4 o; o.x = f2bf(v.x); o.y = f2bf(v.y); o.z = f2bf(v.z); o.w = f2bf(v.w);
        ((ushort4*)xb)[i0 + i * 256] = o;
      }
    } else if (u < 1280){                // Wskip -> bf16
      int i0 = (u - 1024) * 1024 + t;
      #pragma unroll
      for (int i = 0; i < 4; i++){
        float4 v = ((const float4*)Wsk)[i0 + i * 256];
        ushort4 o; o.x = f2bf(v.x); o.y = f2bf(v.y); o.z = f2bf(v.z); o.w = f2bf(v.w);
        ((ushort4*)wb)[i0 + i * 256] = o;
      }
    } else if (u < 3328){                // Wdec -> chunked fp8 e4m3
      int lat0 = (u - 1280) * 8;
      const int chunk = t >> 5;
      const int off   = (t & 31) * 4;
      #pragma unroll
      for (int r = 0; r < 8; r++){
        int lat = lat0 + r;
        float4 v = ((const float4*)(Wd + (size_t)lat * DIM))[t];
        int p = __builtin_amdgcn_cvt_pk_fp8_f32(v.x, v.y, 0, false);
        p     = __builtin_amdgcn_cvt_pk_fp8_f32(v.z, v.w, p, true);
        *(int*)(wdf + ((size_t)chunk * NLAT + lat) * 128 + off) = p;
      }
    } else {                             // ystats partials (no atomics)
      int p = u - 3328;
      const int r0 = p * 32;
      float4 cs = {0.f, 0.f, 0.f, 0.f};
      float sq = 0.f;
      #pragma unroll 4
      for (int r = 0; r < 32; r++){
        float4 v = ((const float4*)(y + (size_t)(r0 + r) * DIM))[t];
        cs.x += v.x; cs.y += v.y; cs.z += v.z; cs.w += v.w;
        sq += v.x*v.x + v.y*v.y + v.z*v.z + v.w*v.w;
      }
      ((float4*)(csp + (size_t)p * 1024))[t] = cs;
      #pragma unroll
      for (int off = 32; off > 0; off >>= 1) sq += __shfl_down(sq, off, 64);
      float* sred = (float*)smem;
      __syncthreads();
      if ((t & 63) == 0) sred[t >> 6] = sq;
      __syncthreads();
      if (t == 0) sqp[p] = sred[0] + sred[1] + sred[2] + sred[3];
      __syncthreads();
    }
  }
  gridbar(bar, bar + 1);

  // ================= P2a: stat reduction (blocks 0..32) =================
  if (bid < 32){
    float* red = (float*)smem;           // [8][32]
    const int c  = bid * 32 + (t & 31);
    const int pg = t >> 5;
    float s = 0.f;
    for (int p = pg; p < 128; p += 8) s += csp[(size_t)p * 1024 + c];
    red[pg * 32 + (t & 31)] = s;
    __syncthreads();
    float cs = 0.f;
    if (t < 32){
      #pragma unroll
      for (int g = 0; g < 8; g++) cs += red[g * 32 + t];
    }
    float v = cs * cs;                   // lanes 32..63 contribute 0
    #pragma unroll
    for (int off = 16; off > 0; off >>= 1) v += __shfl_down(v, off, 64);
    if (t == 0) vp[bid] = v;
  } else if (bid == 32){
    float v2 = (t < 128) ? sqp[t] : 0.f;
    #pragma unroll
    for (int off = 32; off > 0; off >>= 1) v2 += __shfl_down(v2, off, 64);
    float* red2 = (float*)smem;
    if ((t & 63) == 0) red2[t >> 6] = v2;
    __syncthreads();
    if (t == 0) sqf[0] = red2[0] + red2[1] + red2[2] + red2[3];
  }
  __syncthreads();

  // ================= P2b: skip GEMM, one 128x64 tile per block =================
  {
    unsigned short (*As)[32] = (unsigned short(*)[32])smem;          // 8 KB
    unsigned short (*Bs)[32] = (unsigned short(*)[32])(smem + 8192); // 4 KB
    const int row0 = (bid >> 4) * 128;   // 32 row tiles
    const int col0 = (bid & 15) * 64;    // 16 col tiles
    const int lane = t & 63;
    const int w    = t >> 6;
    const int wr   = w * 32;
    const int lm   = lane & 15;
    const int kq   = lane >> 4;
    const int sr   = t >> 2;
    const int sc   = (t & 3) * 8;

    floatx4 acc[2][4] = {};

    for (int k0 = 0; k0 < DIM; k0 += 32){
      __builtin_amdgcn_global_load_lds(GLOBAL_AS(xb + (size_t)(row0 + sr) * DIM + k0 + sc),
                                       LDS_AS(&As[sr][sc]), 16, 0, 0);
      __builtin_amdgcn_global_load_lds(GLOBAL_AS(xb + (size_t)(row0 + 64 + sr) * DIM + k0 + sc),
                                       LDS_AS(&As[64 + sr][sc]), 16, 0, 0);
      __builtin_amdgcn_global_load_lds(GLOBAL_AS(wb + (size_t)(col0 + sr) * DIM + k0 + sc),
                                       LDS_AS(&Bs[sr][sc]), 16, 0, 0);
      __syncthreads();
      bf16x8 af[2], bfr[4];
      #pragma unroll
      for (int mi = 0; mi < 2; mi++) af[mi] = *(const bf16x8*)(&As[wr + mi * 16 + lm][kq * 8]);
      #pragma unroll
      for (int ni = 0; ni < 4; ni++) bfr[ni] = *(const bf16x8*)(&Bs[ni * 16 + lm][kq * 8]);
      #pragma unroll
      for (int mi = 0; mi < 2; mi++)
        #pragma unroll
        for (int ni = 0; ni < 4; ni++)
          acc[mi][ni] = __builtin_amdgcn_mfma_f32_16x16x32_bf16(af[mi], bfr[ni], acc[mi][ni], 0, 0, 0);
      __syncthreads();
    }

    const int rq = (lane >> 4) * 4;      // C/D: col=lane&15, row=(lane>>4)*4+reg
    #pragma unroll
    for (int mi = 0; mi < 2; mi++){
      #pragma unroll
      for (int ni = 0; ni < 4; ni++){
        int col = col0 + ni * 16 + lm;
        float bdv = bd[col];
        #pragma unroll
        for (int r = 0; r < 4; r++){
          int row = row0 + wr + mi * 16 + rq + r;
          out[(size_t)row * DIM + col] = acc[mi][ni][r] + bdv;
        }
      }
    }
  }
  gridbar(bar, bar + 1);

  // ================= P3: decode+residual, 4 virtual blocks =================
  {
    uint2 (*s_ai)[66] = (uint2(*)[66])smem;          // 8448 B
    float* sred = (float*)(smem + 12288);
    const int tl = t >> 4;
    const int cl = t & 15;
    float sacc = 0.f;
    #pragma unroll
    for (int it = 0; it < 4; it++){
      const int vb    = bid + it * NBLK;
      const int chunk = vb & 7;          // constant per block (512 % 8 == 0)
      const int tok0  = (vb >> 3) * 16;
      __syncthreads();
      #pragma unroll
      for (int i = 0; i < 4; i++){
        int e = t + i * 256;
        int tok = e >> 6, k = e & 63;
        int id = li[(tok0 + tok) * KTOP + k];
        float a = (la[(tok0 + tok) * KTOP + k] + pe[id]) * pes[id];
        s_ai[tok][k] = make_uint2(__float_as_uint(a), (unsigned)id * 128u);
      }
      __syncthreads();
      const int n = tok0 + tl;
      const unsigned char* Wbase = wdf + (size_t)chunk * NLAT * 128 + cl * 8;
      float* op = out + (size_t)n * DIM + chunk * 128 + cl * 8;
      const float* yp = y + (size_t)n * DIM + chunk * 128 + cl * 8;
      float4 o0 = ((const float4*)op)[0], o1 = ((const float4*)op)[1];
      float4 y0 = ((const float4*)yp)[0], y1 = ((const float4*)yp)[1];
      float acc[8] = {};
      #pragma unroll 16
      for (int k = 0; k < KTOP; k++){
        uint2 p = s_ai[tl][k];
        const float a = __uint_as_float(p.x);
        const uint2 wv = *(const uint2*)(Wbase + p.y);
        floatx2 c0 = __builtin_amdgcn_cvt_pk_f32_fp8(wv.x, false);
        floatx2 c1 = __builtin_amdgcn_cvt_pk_f32_fp8(wv.x, true);
        floatx2 c2 = __builtin_amdgcn_cvt_pk_f32_fp8(wv.y, false);
        floatx2 c3 = __builtin_amdgcn_cvt_pk_f32_fp8(wv.y, true);
        acc[0] += a * c0.x; acc[1] += a * c0.y;
        acc[2] += a * c1.x; acc[3] += a * c1.y;
        acc[4] += a * c2.x; acc[5] += a * c2.y;
        acc[6] += a * c3.x; acc[7] += a * c3.y;
      }
      acc[0] += o0.x; acc[1] += o0.y; acc[2] += o0.z; acc[3] += o0.w;
      acc[4] += o1.x; acc[5] += o1.y; acc[6] += o1.z; acc[7] += o1.w;
      ((float4*)op)[0] = make_float4(acc[0], acc[1], acc[2], acc[3]);
      ((float4*)op)[1] = make_float4(acc[4], acc[5], acc[6], acc[7]);
      float e0 = y0.x - acc[0], e1 = y0.y - acc[1], e2 = y0.z - acc[2], e3 = y0.w - acc[3];
      float e4 = y1.x - acc[4], e5 = y1.y - acc[5], e6 = y1.z - acc[6], e7 = y1.w - acc[7];
      sacc += e0*e0 + e1*e1 + e2*e2 + e3*e3 + e4*e4 + e5*e5 + e6*e6 + e7*e7;
    }
    #pragma unroll
    for (int off = 32; off > 0; off >>= 1) sacc += __shfl_down(sacc, off, 64);
    if ((t & 63) == 0) sred[t >> 6] = sacc;
    __syncthreads();
    if (t == 0) ssep[bid] = sred[0] + sred[1] + sred[2] + sred[3];
  }
  gridbar(bar, bar + 1);

  // ================= P4: FVU (block 0) =================
  if (bid == 0){
    float s = ssep[t] + ssep[t + 256];
    #pragma unroll
    for (int off = 32; off > 0; off >>= 1) s += __shfl_down(s, off, 64);
    float* sred = (float*)smem;
    __syncthreads();
    if ((t & 63) == 0) sred[t >> 6] = s;
    __syncthreads();
    if (t == 0){
      float sse = sred[0] + sred[1] + sred[2] + sred[3];
      float var = 0.f;
      for (int i = 0; i < 32; i++) var += vp[i];
      float tv = sqf[0] - var / (float)N_TOK;
      out[(size_t)N_TOK * DIM] = sse / tv;
    }
  }
}

extern "C" void kernel_launch(void* const* d_in, const int* in_sizes, int n_in,
                              void* d_out, int out_size, void* d_ws, size_t ws_size,
                              hipStream_t stream){
  const float* x   = (const float*)d_in[0];
  const float* y   = (const float*)d_in[1];
  const float* la  = (const float*)d_in[2];
  const int*   li  = (const int*)d_in[3];
  const float* Wd  = (const float*)d_in[4];
  const float* bd  = (const float*)d_in[5];
  const float* pe  = (const float*)d_in[6];
  const float* pes = (const float*)d_in[7];
  const float* Wsk = (const float*)d_in[8];
  float* out = (float*)d_out;

  char* w = (char*)d_ws;
  unsigned* bar = (unsigned*)w;                                      // 64 B, zeroed below
  unsigned short* xb  = (unsigned short*)(w + 4096);                 // 8 MB
  unsigned short* wb  = (unsigned short*)(w + 4096 + (8u << 20));    // 2 MB
  unsigned char*  wdf = (unsigned char*)(w + 4096 + (10u << 20));    // 16 MB
  float* csp  = (float*)(w + 4096 + (26u << 20));                    // 512 KB
  float* ssep = (float*)(w + 4096 + (26u << 20) + (512u << 10));     // 2 KB
  float* sqp  = ssep + 512;                                          // 512 B
  float* vp   = sqp + 128;                                           // 128 B
  float* sqf  = vp + 32;                                             // 4 B

  hipMemsetAsync(bar, 0, 64, stream);
  fused<<<NBLK, 256, 0, stream>>>(x, y, la, li, Wd, bd, pe, pes, Wsk, out,
                                  bar, xb, wb, wdf, csp, ssep, sqp, vp, sqf);
}

// Round 9
// 241.900 us; speedup vs baseline: 3.1409x; 3.1409x over previous
//
#include <hip/hip_runtime.h>
#include <hip/hip_bf16.h>
#include <cstdint>

#define N_TOK 4096
#define KTOP  64
#define DIM   1024
#define NLAT  16384

typedef __bf16 bf16x8 __attribute__((ext_vector_type(8)));
typedef float  floatx4 __attribute__((ext_vector_type(4)));
typedef float  floatx2 __attribute__((ext_vector_type(2)));

#define GLOBAL_AS(p) ((const __attribute__((address_space(1))) void*)(p))
#define LDS_AS(p)    ((__attribute__((address_space(3))) void*)(p))

__device__ inline unsigned short f2bf(float f){
  unsigned int u = __float_as_uint(f);
  return (unsigned short)((u + 0x7fffu + ((u >> 16) & 1u)) >> 16);  // RNE
}

// Balanced prep: every unit streams ~16KB. Heavy ystats units (64KB, 4x) go FIRST.
// [0,256)      ystats: 16 rows -> csp[b][1024] partials + sqp[b]   (no atomics)
// [256,1280)   x -> bf16 (4 rows/unit)
// [1280,1536)  Wskip -> bf16
// [1536,5632)  Wdec -> chunked fp8 e4m3 (4 latents/unit)
__global__ __launch_bounds__(256) void prep(
    const float* __restrict__ x, const float* __restrict__ Wsk,
    const float* __restrict__ Wd, const float* __restrict__ y,
    unsigned short* __restrict__ xb, unsigned short* __restrict__ wb,
    unsigned char* __restrict__ wdf,
    float* __restrict__ csp, float* __restrict__ sqp,
    unsigned* __restrict__ done){
  const int b = blockIdx.x;
  const int t = threadIdx.x;
  if (b == 0 && t == 0) *done = 0u;   // re-arm the decode completion counter
  if (b < 256){
    const int r0 = b * 16;
    float4 cs = {0.f, 0.f, 0.f, 0.f};
    float sq = 0.f;
    #pragma unroll 4
    for (int r = 0; r < 16; r++){
      float4 v = ((const float4*)(y + (size_t)(r0 + r) * DIM))[t];
      cs.x += v.x; cs.y += v.y; cs.z += v.z; cs.w += v.w;
      sq += v.x*v.x + v.y*v.y + v.z*v.z + v.w*v.w;
    }
    ((float4*)(csp + (size_t)b * DIM))[t] = cs;
    #pragma unroll
    for (int off = 32; off > 0; off >>= 1) sq += __shfl_down(sq, off, 64);
    __shared__ float sred[4];
    if ((t & 63) == 0) sred[t >> 6] = sq;
    __syncthreads();
    if (t == 0) sqp[b] = sred[0] + sred[1] + sred[2] + sred[3];
  } else if (b < 1280){
    int i0 = (b - 256) * 1024 + t;
    #pragma unroll
    for (int i = 0; i < 4; i++){
      float4 v = ((const float4*)x)[i0 + i * 256];
      ushort4 o; o.x = f2bf(v.x); o.y = f2bf(v.y); o.z = f2bf(v.z); o.w = f2bf(v.w);
      ((ushort4*)xb)[i0 + i * 256] = o;
    }
  } else if (b < 1536){
    int i0 = (b - 1280) * 1024 + t;
    #pragma unroll
    for (int i = 0; i < 4; i++){
      float4 v = ((const float4*)Wsk)[i0 + i * 256];
      ushort4 o; o.x = f2bf(v.x); o.y = f2bf(v.y); o.z = f2bf(v.z); o.w = f2bf(v.w);
      ((ushort4*)wb)[i0 + i * 256] = o;
    }
  } else {
    int lat0 = (b - 1536) * 4;
    const int chunk = t >> 5;
    const int off   = (t & 31) * 4;
    #pragma unroll
    for (int r = 0; r < 4; r++){
      int lat = lat0 + r;
      float4 v = ((const float4*)(Wd + (size_t)lat * DIM))[t];
      int p = __builtin_amdgcn_cvt_pk_fp8_f32(v.x, v.y, 0, false);
      p     = __builtin_amdgcn_cvt_pk_fp8_f32(v.z, v.w, p, true);
      *(int*)(wdf + ((size_t)chunk * NLAT + lat) * 128 + off) = p;
    }
  }
}

// R4-proven 128x64 bf16 GEMM (512 blocks) + stats-reduction prologue in blocks 0..256.
__global__ __launch_bounds__(256) void skip_gemm(
    const unsigned short* __restrict__ xb,
    const unsigned short* __restrict__ wb,
    const float* __restrict__ b_dec,
    const float* __restrict__ csp, const float* __restrict__ sqp,
    float* __restrict__ vp, float* __restrict__ sqf,
    float* __restrict__ out){
  __shared__ unsigned short As[128][32];
  __shared__ unsigned short Bs[64][32];
  __shared__ float sred[4];
  const int bid = blockIdx.y * 32 + blockIdx.x;
  const int t   = threadIdx.x;

  if (bid < 256){                       // colsum reduce: 4 cols/block, 16KB read
    const int g    = t >> 6;
    const int lane = t & 63;
    const int col  = bid * 4 + g;
    float s = 0.f;
    #pragma unroll
    for (int j = 0; j < 4; j++) s += csp[(size_t)(lane + 64 * j) * DIM + col];
    #pragma unroll
    for (int off = 32; off > 0; off >>= 1) s += __shfl_down(s, off, 64);
    if (lane == 0) sred[g] = s * s;
    __syncthreads();
    if (t == 0) vp[bid] = sred[0] + sred[1] + sred[2] + sred[3];
  } else if (bid == 256){               // sumsq reduce
    float v = sqp[t];
    #pragma unroll
    for (int off = 32; off > 0; off >>= 1) v += __shfl_down(v, off, 64);
    if ((t & 63) == 0) sred[t >> 6] = v;
    __syncthreads();
    if (t == 0) sqf[0] = sred[0] + sred[1] + sred[2] + sred[3];
  }
  __syncthreads();

  const int row0 = blockIdx.x * 128;
  const int col0 = blockIdx.y * 64;
  const int lane = t & 63;
  const int w    = t >> 6;
  const int wr   = w * 32;
  const int lm   = lane & 15;
  const int kq   = lane >> 4;
  const int sr   = t >> 2;
  const int sc   = (t & 3) * 8;

  floatx4 acc[2][4] = {};

  for (int k0 = 0; k0 < DIM; k0 += 32){
    __builtin_amdgcn_global_load_lds(GLOBAL_AS(xb + (size_t)(row0 + sr) * DIM + k0 + sc),
                                     LDS_AS(&As[sr][sc]), 16, 0, 0);
    __builtin_amdgcn_global_load_lds(GLOBAL_AS(xb + (size_t)(row0 + 64 + sr) * DIM + k0 + sc),
                                     LDS_AS(&As[64 + sr][sc]), 16, 0, 0);
    __builtin_amdgcn_global_load_lds(GLOBAL_AS(wb + (size_t)(col0 + sr) * DIM + k0 + sc),
                                     LDS_AS(&Bs[sr][sc]), 16, 0, 0);
    __syncthreads();
    bf16x8 af[2], bfr[4];
    #pragma unroll
    for (int mi = 0; mi < 2; mi++) af[mi] = *(const bf16x8*)(&As[wr + mi * 16 + lm][kq * 8]);
    #pragma unroll
    for (int ni = 0; ni < 4; ni++) bfr[ni] = *(const bf16x8*)(&Bs[ni * 16 + lm][kq * 8]);
    #pragma unroll
    for (int mi = 0; mi < 2; mi++)
      #pragma unroll
      for (int ni = 0; ni < 4; ni++)
        acc[mi][ni] = __builtin_amdgcn_mfma_f32_16x16x32_bf16(af[mi], bfr[ni], acc[mi][ni], 0, 0, 0);
    __syncthreads();
  }

  const int rq = (lane >> 4) * 4;       // C/D: col=lane&15, row=(lane>>4)*4+reg
  #pragma unroll
  for (int mi = 0; mi < 2; mi++){
    #pragma unroll
    for (int ni = 0; ni < 4; ni++){
      int col = col0 + ni * 16 + lm;
      float bdv = b_dec[col];
      #pragma unroll
      for (int r = 0; r < 4; r++){
        int row = row0 + wr + mi * 16 + rq + r;
        out[(size_t)row * DIM + col] = acc[mi][ni][r] + bdv;
      }
    }
  }
}

// Decode: 32 tokens/block, 8 threads/row @ 16B gathers (half the L2 requests).
// Last block (device-scope counter) reduces partials and writes FVU.
__global__ __launch_bounds__(256) void decode_residual(
    const float* __restrict__ y,
    const float* __restrict__ la,
    const int*   __restrict__ li,
    const unsigned char* __restrict__ wdf,   // [8][NLAT][128] fp8 e4m3
    const float* __restrict__ pe,
    const float* __restrict__ pes,
    float* __restrict__ out,
    float* __restrict__ ssep,
    const float* __restrict__ vp, const float* __restrict__ sqf,
    unsigned* __restrict__ done){
  const int bid   = blockIdx.x;        // 1024
  const int chunk = bid & 7;
  const int tok0  = (bid >> 3) * 32;
  const int t  = threadIdx.x;
  const int tl = t >> 3;               // token lane 0..31
  const int cl = t & 7;                // col lane: 16 cols each
  __shared__ uint2 s_ai[32][65];       // stride 65 -> conflict-free across tl
  __shared__ float sred[4], sred2[4];
  __shared__ int lastflag;
  #pragma unroll
  for (int i = 0; i < 8; i++){
    int e = t + i * 256;               // 2048 entries
    int tok = e >> 6, k = e & 63;
    int id = li[(tok0 + tok) * KTOP + k];
    float a = (la[(tok0 + tok) * KTOP + k] + pe[id]) * pes[id];
    s_ai[tok][k] = make_uint2(__float_as_uint(a), (unsigned)id * 128u);
  }
  __syncthreads();
  const int n = tok0 + tl;
  const unsigned char* Wbase = wdf + (size_t)chunk * NLAT * 128 + cl * 16;
  float* op = out + (size_t)n * DIM + chunk * 128 + cl * 16;
  const float* yp = y + (size_t)n * DIM + chunk * 128 + cl * 16;
  float acc[16] = {};
  #pragma unroll 8
  for (int k = 0; k < KTOP; k++){
    uint2 p = s_ai[tl][k];
    const float a = __uint_as_float(p.x);
    const uint4 wv = *(const uint4*)(Wbase + p.y);
    floatx2 c;
    c = __builtin_amdgcn_cvt_pk_f32_fp8(wv.x, false); acc[0]  += a*c.x; acc[1]  += a*c.y;
    c = __builtin_amdgcn_cvt_pk_f32_fp8(wv.x, true ); acc[2]  += a*c.x; acc[3]  += a*c.y;
    c = __builtin_amdgcn_cvt_pk_f32_fp8(wv.y, false); acc[4]  += a*c.x; acc[5]  += a*c.y;
    c = __builtin_amdgcn_cvt_pk_f32_fp8(wv.y, true ); acc[6]  += a*c.x; acc[7]  += a*c.y;
    c = __builtin_amdgcn_cvt_pk_f32_fp8(wv.z, false); acc[8]  += a*c.x; acc[9]  += a*c.y;
    c = __builtin_amdgcn_cvt_pk_f32_fp8(wv.z, true ); acc[10] += a*c.x; acc[11] += a*c.y;
    c = __builtin_amdgcn_cvt_pk_f32_fp8(wv.w, false); acc[12] += a*c.x; acc[13] += a*c.y;
    c = __builtin_amdgcn_cvt_pk_f32_fp8(wv.w, true ); acc[14] += a*c.x; acc[15] += a*c.y;
  }
  float s = 0.f;
  #pragma unroll
  for (int q = 0; q < 4; q++){
    float4 o  = ((const float4*)op)[q];
    float4 yv = ((const float4*)yp)[q];
    float4 r;
    r.x = acc[4*q+0] + o.x; r.y = acc[4*q+1] + o.y;
    r.z = acc[4*q+2] + o.z; r.w = acc[4*q+3] + o.w;
    ((float4*)op)[q] = r;
    float e0 = yv.x - r.x, e1 = yv.y - r.y, e2 = yv.z - r.z, e3 = yv.w - r.w;
    s += e0*e0 + e1*e1 + e2*e2 + e3*e3;
  }
  #pragma unroll
  for (int off = 32; off > 0; off >>= 1) s += __shfl_down(s, off, 64);
  if ((t & 63) == 0) sred[t >> 6] = s;
  __syncthreads();
  if (t == 0){
    ssep[bid] = sred[0] + sred[1] + sred[2] + sred[3];
    unsigned old = __hip_atomic_fetch_add(done, 1u, __ATOMIC_ACQ_REL, __HIP_MEMORY_SCOPE_AGENT);
    lastflag = (old == 1023u);
  }
  __syncthreads();
  if (lastflag){                        // final FVU, once per launch
    float v = ssep[t] + ssep[t + 256] + ssep[t + 512] + ssep[t + 768];
    float w = vp[t];                    // vp[256] valid for t<256
    #pragma unroll
    for (int off = 32; off > 0; off >>= 1){
      v += __shfl_down(v, off, 64);
      w += __shfl_down(w, off, 64);
    }
    if ((t & 63) == 0){ sred[t >> 6] = v; sred2[t >> 6] = w; }
    __syncthreads();
    if (t == 0){
      float sse = sred[0] + sred[1] + sred[2] + sred[3];
      float var = sred2[0] + sred2[1] + sred2[2] + sred2[3];
      float tv  = sqf[0] - var / (float)N_TOK;
      out[(size_t)N_TOK * DIM] = sse / tv;
    }
  }
}

extern "C" void kernel_launch(void* const* d_in, const int* in_sizes, int n_in,
                              void* d_out, int out_size, void* d_ws, size_t ws_size,
                              hipStream_t stream){
  const float* x   = (const float*)d_in[0];
  const float* y   = (const float*)d_in[1];
  const float* la  = (const float*)d_in[2];
  const int*   li  = (const int*)d_in[3];
  const float* Wd  = (const float*)d_in[4];
  const float* bd  = (const float*)d_in[5];
  const float* pe  = (const float*)d_in[6];
  const float* pes = (const float*)d_in[7];
  const float* Wsk = (const float*)d_in[8];
  float* out = (float*)d_out;

  char* w = (char*)d_ws;
  unsigned short* xb  = (unsigned short*)(w);                    // 8 MB
  unsigned short* wb  = (unsigned short*)(w + (8u << 20));       // 2 MB
  unsigned char*  wdf = (unsigned char*)(w + (10u << 20));       // 16 MB
  float* csp  = (float*)(w + (26u << 20));                       // 1 MB [256][1024]
  float* sqp  = (float*)(w + (27u << 20));                       // 1 KB [256]
  float* vp   = (float*)(w + (27u << 20) + 4096);                // 1 KB [256]
  float* sqf  = (float*)(w + (27u << 20) + 8192);                // 4 B
  float* ssep = (float*)(w + (27u << 20) + 12288);               // 4 KB [1024]
  unsigned* done = (unsigned*)(w + (27u << 20) + 28672);         // 4 B

  prep<<<5632, 256, 0, stream>>>(x, Wsk, Wd, y, xb, wb, wdf, csp, sqp, done);
  skip_gemm<<<dim3(32, 16), 256, 0, stream>>>(xb, wb, bd, csp, sqp, vp, sqf, out);
  decode_residual<<<1024, 256, 0, stream>>>(y, la, li, wdf, pe, pes, out, ssep, vp, sqf, done);
}